// Round 1
// baseline (94.029 us; speedup 1.0000x reference)
//
#include <hip/hip_runtime.h>
#include <hip/hip_bf16.h>

#define LDIM 4096
#define BDIM 4
#define DDIM 64

typedef __attribute__((ext_vector_type(4))) float f32x4;
typedef __attribute__((ext_vector_type(8))) __bf16 bf16x8;

// Stage 1: Q[b,m,d] = sum_e K[d,e] * t1[m,b,e]  (bf16 out),
//          A[b,m,d] = bf16(t0[m,b,d])           (repack for per-b GEMM)
__global__ __launch_bounds__(256) void prep_kernel(
    const float* __restrict__ t0,
    const float* __restrict__ t1,
    const float* __restrict__ kmat,
    __hip_bfloat16* __restrict__ Abf,
    __hip_bfloat16* __restrict__ Qbf)
{
    __shared__ float kT[DDIM][DDIM];   // kT[e][d] = kmat[d][e] (transposed: conflict-free reads)
    __shared__ float rows[4][DDIM];
    const int tid = threadIdx.x;
    for (int i = tid; i < DDIM * DDIM; i += 256) {
        const int d = i >> 6, e = i & 63;
        kT[e][d] = kmat[i];            // kmat[d*64 + e]
    }
    const int sub = tid >> 6;          // which of 4 rows this block handles
    const int d   = tid & 63;
    const int r   = blockIdx.x * 4 + sub;   // r = m*B + b (flat row of [L,B] majors)
    rows[sub][d] = t1[(size_t)r * DDIM + d];
    __syncthreads();

    float acc = 0.f;
#pragma unroll
    for (int e = 0; e < DDIM; ++e)
        acc = fmaf(kT[e][d], rows[sub][e], acc);   // rows[sub][e] broadcasts; kT row is consecutive

    const int m = r >> 2;   // r / B
    const int b = r & 3;    // r % B
    const size_t o = ((size_t)(b * LDIM) + m) * DDIM + d;
    Qbf[o] = __float2bfloat16(acc);
    Abf[o] = __float2bfloat16(t0[(size_t)r * DDIM + d]);
}

// Stage 2: per-b GEMM, C[b][l][m] = sum_d A[b][l][d] * Q[b][m][d] + bias.
// 128x128 tile per block, 4 waves of 64x64, K=64 fully in registers (no LDS).
__global__ __launch_bounds__(256) void gemm_kernel(
    const __hip_bfloat16* __restrict__ Abf,
    const __hip_bfloat16* __restrict__ Qbf,
    const float* __restrict__ bias,
    float* __restrict__ out)
{
    const int bid = blockIdx.x;
    const int b   = bid >> 10;       // / (32*32)
    const int t   = bid & 1023;
    const int tr  = t >> 5;          // tile row (of 32)
    const int tc  = t & 31;          // tile col
    const int w    = threadIdx.x >> 6;
    const int lane = threadIdx.x & 63;
    const int wr = w >> 1, wc = w & 1;      // 2x2 waves -> 64x64 each
    const int lr  = lane & 15;
    const int lhi = lane >> 4;

    const __hip_bfloat16* A  = Abf + (size_t)b * LDIM * DDIM;
    const __hip_bfloat16* Bq = Qbf + (size_t)b * LDIM * DDIM;

    // A fragment: lane holds A[row = base + (lane&15)][k = (lane>>4)*8 + j], 8 contiguous bf16 = 16B
    bf16x8 af[4][2], bf[4][2];
#pragma unroll
    for (int mi = 0; mi < 4; ++mi) {
        const int row = tr * 128 + wr * 64 + mi * 16 + lr;
#pragma unroll
        for (int ks = 0; ks < 2; ++ks)
            af[mi][ks] = *(const bf16x8*)(A + (size_t)row * DDIM + ks * 32 + lhi * 8);
    }
#pragma unroll
    for (int ni = 0; ni < 4; ++ni) {
        const int row = tc * 128 + wc * 64 + ni * 16 + lr;
#pragma unroll
        for (int ks = 0; ks < 2; ++ks)
            bf[ni][ks] = *(const bf16x8*)(Bq + (size_t)row * DDIM + ks * 32 + lhi * 8);
    }

    f32x4 acc[4][4] = {};
#pragma unroll
    for (int ks = 0; ks < 2; ++ks)
#pragma unroll
        for (int mi = 0; mi < 4; ++mi)
#pragma unroll
            for (int ni = 0; ni < 4; ++ni)
                acc[mi][ni] = __builtin_amdgcn_mfma_f32_16x16x32_bf16(
                    af[mi][ks], bf[ni][ks], acc[mi][ni], 0, 0, 0);

    const float bs = bias[0];
    float* outb = out + (size_t)b * LDIM * LDIM;
    // C/D layout: col = lane&15, row = (lane>>4)*4 + j
#pragma unroll
    for (int mi = 0; mi < 4; ++mi) {
#pragma unroll
        for (int ni = 0; ni < 4; ++ni) {
            const int col = tc * 128 + wc * 64 + ni * 16 + lr;
#pragma unroll
            for (int j = 0; j < 4; ++j) {
                const int row = tr * 128 + wr * 64 + mi * 16 + lhi * 4 + j;
                outb[(size_t)row * LDIM + col] = acc[mi][ni][j] + bs;
            }
        }
    }
}

extern "C" void kernel_launch(void* const* d_in, const int* in_sizes, int n_in,
                              void* d_out, int out_size, void* d_ws, size_t ws_size,
                              hipStream_t stream) {
    const float* t0   = (const float*)d_in[0];
    const float* t1   = (const float*)d_in[1];
    const float* km   = (const float*)d_in[2];
    const float* bias = (const float*)d_in[3];
    float* out = (float*)d_out;

    __hip_bfloat16* Abf = (__hip_bfloat16*)d_ws;                 // [B][L][D] bf16 = 2 MB
    __hip_bfloat16* Qbf = Abf + (size_t)BDIM * LDIM * DDIM;      // [B][L][D] bf16 = 2 MB

    prep_kernel<<<LDIM * BDIM / 4, 256, 0, stream>>>(t0, t1, km, Abf, Qbf);
    gemm_kernel<<<BDIM * 32 * 32, 256, 0, stream>>>(Abf, Qbf, bias, out);
}